// Round 1
// baseline (371.508 us; speedup 1.0000x reference)
//
#include <hip/hip_runtime.h>
#include <math.h>

static constexpr int Bb = 64, Tt = 256, Dd = 64, Hh = 128;
static constexpr int BT = Bb * Tt;   // 16384

// ---------------------------------------------------------------------------
// Kernel 1: conv1d over time (K=3, SAME) + bias + ReLU.
// h0[b,t,h] = relu(sum_{d,k} x[b,t+k-1,d] * w[h,d,k] + bias[h])
// grid: 64 b x 8 tchunks(32) x 2 hhalf = 1024 blocks, 256 threads.
// LDS: xsT[d][r] (x transposed, 34-row halo tile) + ws[dk][hl] (w transposed,
// pad 65 so lane reads stride-1, conflict-free). 59 KB total.
// ---------------------------------------------------------------------------
__global__ __launch_bounds__(256) void conv_relu_k(
    const float* __restrict__ x, const float* __restrict__ w,
    const float* __restrict__ bias, float* __restrict__ h0)
{
    __shared__ float xsT[64][36];        // [d][r], r=0..33 -> t = t0-1+r
    __shared__ float ws[192 * 65];       // ws[dk*65 + hl]
    const int tid   = threadIdx.x;
    const int b     = blockIdx.x >> 4;
    const int chunk = (blockIdx.x >> 1) & 7;
    const int hhalf = blockIdx.x & 1;
    const int t0 = chunk * 32;

    for (int i = tid; i < 34 * 64; i += 256) {
        const int r = i >> 6, d = i & 63;
        const int t = t0 - 1 + r;
        float v = 0.f;
        if (t >= 0 && t < Tt) v = x[(b * Tt + t) * Dd + d];
        xsT[d][r] = v;
    }
    for (int i = tid; i < 64 * 192; i += 256) {
        const int hl = i / 192;
        const int dk = i - hl * 192;
        ws[dk * 65 + hl] = w[(hhalf * 64 + hl) * 192 + dk];
    }
    __syncthreads();

    const int hl   = tid & 63;   // wave-uniform tg: lanes 0..63 share tg
    const int tg   = tid >> 6;   // 0..3
    const int base = tg * 8;

    float acc[8];
    const float bv = bias[hhalf * 64 + hl];
    #pragma unroll
    for (int i = 0; i < 8; ++i) acc[i] = bv;

    for (int d = 0; d < 64; ++d) {
        const float w0 = ws[(d * 3 + 0) * 65 + hl];
        const float w1 = ws[(d * 3 + 1) * 65 + hl];
        const float w2 = ws[(d * 3 + 2) * 65 + hl];
        float xv[10];
        const float4 p0 = *(const float4*)&xsT[d][base];
        const float4 p1 = *(const float4*)&xsT[d][base + 4];
        xv[0]=p0.x; xv[1]=p0.y; xv[2]=p0.z; xv[3]=p0.w;
        xv[4]=p1.x; xv[5]=p1.y; xv[6]=p1.z; xv[7]=p1.w;
        xv[8] = xsT[d][base + 8];
        xv[9] = xsT[d][base + 9];
        #pragma unroll
        for (int tt = 0; tt < 8; ++tt)
            acc[tt] = fmaf(xv[tt], w0, fmaf(xv[tt+1], w1, fmaf(xv[tt+2], w2, acc[tt])));
    }

    #pragma unroll
    for (int tt = 0; tt < 8; ++tt) {
        const int t = t0 + base + tt;
        h0[(b * Tt + t) * Hh + hhalf * 64 + hl] = fmaxf(acc[tt], 0.f);
    }
}

// ---------------------------------------------------------------------------
// Kernel 2/3: C[m, n0+n] = relu(A[m,:] @ W[:, n0+n] + bias[n0+n])
// M=16384, K=128, BM=64, BN=64. grid = 256 rowblocks x 2 colblocks.
// 256 threads, 4x4 microtile. LDS = 32 KB A-tile (contiguous rows, flat f4
// copy) + 32 KB W-slab = 64 KB exactly.
// ---------------------------------------------------------------------------
__global__ __launch_bounds__(256) void gemm_relu_k(
    const float* __restrict__ A, const float* __restrict__ W,
    const float* __restrict__ bias, float* __restrict__ C)
{
    __shared__ float As[64 * 128];
    __shared__ float Ws[128 * 64];
    const int tid  = threadIdx.x;
    const int rowb = blockIdx.x & 255;
    const int colb = blockIdx.x >> 8;
    const int row0 = rowb * 64;
    const int n0   = colb * 64;

    const float4* Asrc = (const float4*)(A + row0 * 128);
    float4* Adst = (float4*)As;
    for (int i = tid; i < 2048; i += 256) Adst[i] = Asrc[i];
    for (int i = tid; i < 128 * 16; i += 256) {
        const int k = i >> 4, nq = i & 15;
        *(float4*)&Ws[k * 64 + nq * 4] = *(const float4*)&W[k * 128 + n0 + nq * 4];
    }
    __syncthreads();

    const int cg = tid & 15, rg = tid >> 4;
    const int c0 = cg * 4, r0 = rg * 4;
    float acc[4][4] = {};
    #pragma unroll 8
    for (int k = 0; k < 128; ++k) {
        const float4 wv = *(const float4*)&Ws[k * 64 + c0];
        #pragma unroll
        for (int i = 0; i < 4; ++i) {
            const float a = As[(r0 + i) * 128 + k];
            acc[i][0] = fmaf(a, wv.x, acc[i][0]);
            acc[i][1] = fmaf(a, wv.y, acc[i][1]);
            acc[i][2] = fmaf(a, wv.z, acc[i][2]);
            acc[i][3] = fmaf(a, wv.w, acc[i][3]);
        }
    }
    const float4 bv = *(const float4*)&bias[n0 + c0];
    #pragma unroll
    for (int i = 0; i < 4; ++i) {
        float4 o;
        o.x = fmaxf(acc[i][0] + bv.x, 0.f);
        o.y = fmaxf(acc[i][1] + bv.y, 0.f);
        o.z = fmaxf(acc[i][2] + bv.z, 0.f);
        o.w = fmaxf(acc[i][3] + bv.w, 0.f);
        *(float4*)&C[(row0 + r0 + i) * 128 + n0 + c0] = o;
    }
}

// ---------------------------------------------------------------------------
// Kernel 4: head mapped = h2 @ w3 + b3 (N=48) fused with epilogue:
//   c<16  -> mean[b,c,t] = v
//   c>=16 -> (only t%16<8) scale[b, t>>4, i, i] = 1/(1+softplus(v)),
//            i = (t&15)*32 + (c-16)
// d_out assumed pre-zeroed (memset). BM=64, 256 threads, 4x3 microtile.
// ---------------------------------------------------------------------------
__global__ __launch_bounds__(256) void head_k(
    const float* __restrict__ A, const float* __restrict__ W3,
    const float* __restrict__ b3, float* __restrict__ out)
{
    __shared__ float As[64 * 128];   // 32 KB
    __shared__ float Ws[128 * 48];   // 24 KB
    const int tid  = threadIdx.x;
    const int row0 = blockIdx.x * 64;

    const float4* Asrc = (const float4*)(A + row0 * 128);
    float4* Adst = (float4*)As;
    for (int i = tid; i < 2048; i += 256) Adst[i] = Asrc[i];
    const float4* Wsrc = (const float4*)W3;
    float4* Wdst = (float4*)Ws;
    for (int i = tid; i < 128 * 12; i += 256) Wdst[i] = Wsrc[i];
    __syncthreads();

    const int cg = tid & 15, rg = tid >> 4;
    const int c0 = cg * 3, r0 = rg * 4;
    float acc[4][3] = {};
    #pragma unroll 8
    for (int k = 0; k < 128; ++k) {
        const float w0 = Ws[k * 48 + c0 + 0];
        const float w1 = Ws[k * 48 + c0 + 1];
        const float w2 = Ws[k * 48 + c0 + 2];
        #pragma unroll
        for (int i = 0; i < 4; ++i) {
            const float a = As[(r0 + i) * 128 + k];
            acc[i][0] = fmaf(a, w0, acc[i][0]);
            acc[i][1] = fmaf(a, w1, acc[i][1]);
            acc[i][2] = fmaf(a, w2, acc[i][2]);
        }
    }
    #pragma unroll
    for (int i = 0; i < 4; ++i) {
        const int row = row0 + r0 + i;
        const int b = row >> 8, t = row & 255;
        #pragma unroll
        for (int j = 0; j < 3; ++j) {
            const int c = c0 + j;
            const float v = acc[i][j] + b3[c];
            if (c < 16) {
                out[(b * 16 + c) * 256 + t] = v;               // mean
            } else if ((t & 15) < 8) {                          // diag only
                const int cc = c - 16;
                const int l  = t >> 4;
                const int ii = (t & 15) * 32 + cc;
                const float sp = (v > 15.f) ? v : log1pf(expf(v));
                out[(size_t)262144 + (size_t)((b * 16 + l) * 256 + ii) * 256 + ii]
                    = 1.f / (1.f + sp);
            }
            // t%16 >= 8 feeds the superdiagonal band, which lower=True
            // triangular solve ignores -> contributes nothing to output.
        }
    }
}

extern "C" void kernel_launch(void* const* d_in, const int* in_sizes, int n_in,
                              void* d_out, int out_size, void* d_ws, size_t ws_size,
                              hipStream_t stream) {
    const float* x      = (const float*)d_in[0];
    const float* conv_w = (const float*)d_in[1];
    const float* conv_b = (const float*)d_in[2];
    const float* w1     = (const float*)d_in[3];
    const float* b1     = (const float*)d_in[4];
    const float* w2     = (const float*)d_in[5];
    const float* b2     = (const float*)d_in[6];
    const float* w3     = (const float*)d_in[7];
    const float* b3     = (const float*)d_in[8];
    float* out = (float*)d_out;

    float* h0 = (float*)d_ws;                    // 16384 x 128
    float* h1 = h0 + (size_t)BT * Hh;            // 16384 x 128 (16 MB total ws)

    // Zero the whole output (mean fully overwritten; scale needs zeros
    // everywhere off-diagonal). ~269.5 MB -> the memory-bound floor.
    hipMemsetAsync(d_out, 0, (size_t)out_size * sizeof(float), stream);

    conv_relu_k<<<1024, 256, 0, stream>>>(x, conv_w, conv_b, h0);
    gemm_relu_k<<<512, 256, 0, stream>>>(h0, w1, b1, h1);
    gemm_relu_k<<<512, 256, 0, stream>>>(h1, w2, b2, h0);   // h0 reused as h2
    head_k<<<256, 256, 0, stream>>>(h0, w3, b3, out);
}